// Round 1
// baseline (169.648 us; speedup 1.0000x reference)
//
#include <hip/hip_runtime.h>
#include <math.h>

#define T_LEN 256
#define HID 10
#define G4 40

typedef float v2f __attribute__((ext_vector_type(2)));

__device__ __forceinline__ v2f mk2(float a, float b) { v2f r; r.x = a; r.y = b; return r; }

// stable softplus, matches jax.nn.softplus numerics (startup only, accurate libm)
__device__ __forceinline__ float softplus_f(float x) {
    return fmaxf(x, 0.0f) + log1pf(expf(-fabsf(x)));
}

__device__ __forceinline__ float samp(const float* mu, const float* rho,
                                      const float* eps, int i) {
    return mu[i] + softplus_f(rho[i]) * eps[i];
}

// fast sigmoid: rcp(1+exp(-x)); v_exp_f32 + v_rcp_f32, ~1ulp each
__device__ __forceinline__ float fast_sigmoid(float x) {
    return __builtin_amdgcn_rcpf(1.0f + __expf(-x));
}

// tanh(x) = 1 - 2/(exp(2x)+1); saturates correctly at +/-inf
__device__ __forceinline__ float fast_tanh(float x) {
    float e = __expf(2.0f * x);
    return 1.0f - 2.0f * __builtin_amdgcn_rcpf(e + 1.0f);
}

__global__ __launch_bounds__(256) void bayes_lstm_kernel(
    const float* __restrict__ x,
    const float* __restrict__ w_ih_mu, const float* __restrict__ w_ih_rho,
    const float* __restrict__ w_hh_mu, const float* __restrict__ w_hh_rho,
    const float* __restrict__ b_mu,    const float* __restrict__ b_rho,
    const float* __restrict__ eps_ih,  const float* __restrict__ eps_hh,
    const float* __restrict__ eps_b,
    const float* __restrict__ lin_w,   const float* __restrict__ lin_b,
    float* __restrict__ out)
{
    const int tid   = threadIdx.x;
    const int k     = tid & 15;        // hidden-unit lane within group (active: k<10)
    const int group = tid >> 4;        // 16 groups per block
    const int b     = blockIdx.x * 16 + group;

    // ---- sample weights into registers (zero-padded for lanes 10..15) ----
    // whh01[j] = { W_hh[j, 0*10+k], W_hh[j, 1*10+k] }  (i, f columns)
    // whh23[j] = { W_hh[j, 2*10+k], W_hh[j, 3*10+k] }  (g, o columns)
    v2f whh01[HID], whh23[HID];
    v2f wih01 = mk2(0.f, 0.f), wih23 = mk2(0.f, 0.f);
    v2f b01   = mk2(0.f, 0.f), b23   = mk2(0.f, 0.f);
#pragma unroll
    for (int j = 0; j < HID; ++j) { whh01[j] = mk2(0.f, 0.f); whh23[j] = mk2(0.f, 0.f); }

    if (k < HID) {
        const int c0 = 0 * HID + k, c1 = 1 * HID + k, c2 = 2 * HID + k, c3 = 3 * HID + k;
        wih01 = mk2(samp(w_ih_mu, w_ih_rho, eps_ih, c0), samp(w_ih_mu, w_ih_rho, eps_ih, c1));
        wih23 = mk2(samp(w_ih_mu, w_ih_rho, eps_ih, c2), samp(w_ih_mu, w_ih_rho, eps_ih, c3));
        b01   = mk2(samp(b_mu, b_rho, eps_b, c0), samp(b_mu, b_rho, eps_b, c1));
        b23   = mk2(samp(b_mu, b_rho, eps_b, c2), samp(b_mu, b_rho, eps_b, c3));
#pragma unroll
        for (int j = 0; j < HID; ++j) {
            whh01[j] = mk2(samp(w_hh_mu, w_hh_rho, eps_hh, j * G4 + c0),
                           samp(w_hh_mu, w_hh_rho, eps_hh, j * G4 + c1));
            whh23[j] = mk2(samp(w_hh_mu, w_hh_rho, eps_hh, j * G4 + c2),
                           samp(w_hh_mu, w_hh_rho, eps_hh, j * G4 + c3));
        }
    }

    // ---- LSTM recurrence ----
    float h_all[HID];                  // replicated h (every lane holds full h)
#pragma unroll
    for (int j = 0; j < HID; ++j) h_all[j] = 0.0f;
    float c = 0.0f;

    const float* xrow = x + (size_t)b * T_LEN;
    float xcur = xrow[k];              // chunk 0: lane k holds x[t = k]

    for (int to = 0; to < 16; ++to) {
        float xnext = 0.0f;
        if (to < 15) xnext = xrow[(to + 1) * 16 + k];   // prefetch next chunk

#pragma unroll
        for (int ti = 0; ti < 16; ++ti) {
            // broadcast x_t (t = to*16 + ti) from lane ti of this group
            float xt = __shfl(xcur, ti, 16);
            v2f xt2 = mk2(xt, xt);
            v2f acc01 = __builtin_elementwise_fma(xt2, wih01, b01);   // {i_pre, f_pre}
            v2f acc23 = __builtin_elementwise_fma(xt2, wih23, b23);   // {g_pre, o_pre}
#pragma unroll
            for (int j = 0; j < HID; ++j) {
                v2f hj2 = mk2(h_all[j], h_all[j]);
                acc01 = __builtin_elementwise_fma(hj2, whh01[j], acc01);
                acc23 = __builtin_elementwise_fma(hj2, whh23[j], acc23);
            }
            float ig = fast_sigmoid(acc01.x);
            float fg = fast_sigmoid(acc01.y);
            float gg = fast_tanh(acc23.x);
            float og = fast_sigmoid(acc23.y);
            c = fmaf(fg, c, ig * gg);
            float hk = og * fast_tanh(c);
            // broadcast updated h to all lanes of the group
#pragma unroll
            for (int j = 0; j < HID; ++j) h_all[j] = __shfl(hk, j, 16);
        }
        xcur = xnext;
    }

    // ---- linear head: every lane has full h; lane 0 writes ----
    if (k == 0) {
        float o = lin_b[0];
#pragma unroll
        for (int j = 0; j < HID; ++j) o = fmaf(h_all[j], lin_w[j], o);
        out[b] = o;
    }
}

extern "C" void kernel_launch(void* const* d_in, const int* in_sizes, int n_in,
                              void* d_out, int out_size, void* d_ws, size_t ws_size,
                              hipStream_t stream) {
    const float* x        = (const float*)d_in[0];
    const float* w_ih_mu  = (const float*)d_in[1];
    const float* w_ih_rho = (const float*)d_in[2];
    const float* w_hh_mu  = (const float*)d_in[3];
    const float* w_hh_rho = (const float*)d_in[4];
    const float* b_mu     = (const float*)d_in[5];
    const float* b_rho    = (const float*)d_in[6];
    const float* eps_ih   = (const float*)d_in[7];
    const float* eps_hh   = (const float*)d_in[8];
    const float* eps_b    = (const float*)d_in[9];
    const float* lin_w    = (const float*)d_in[10];
    const float* lin_b    = (const float*)d_in[11];
    float* out = (float*)d_out;

    const int n_b = in_sizes[0] / T_LEN;     // 8192
    dim3 grid(n_b / 16), block(256);
    hipLaunchKernelGGL(bayes_lstm_kernel, grid, block, 0, stream,
                       x, w_ih_mu, w_ih_rho, w_hh_mu, w_hh_rho, b_mu, b_rho,
                       eps_ih, eps_hh, eps_b, lin_w, lin_b, out);
}

// Round 2
// 168.301 us; speedup vs baseline: 1.0080x; 1.0080x over previous
//
#include <hip/hip_runtime.h>
#include <math.h>

#define T_LEN 256
#define HID 10

typedef float v2f __attribute__((ext_vector_type(2)));

__device__ __forceinline__ v2f mk2(float a, float b) { v2f r; r.x = a; r.y = b; return r; }

// ds_swizzle with compile-time pattern (BitMode: offset = (xor<<10)|(or<<5)|and)
// broadcast lane j within 16-lane group: src = (lane & 0x10) | j  -> PAT = (j<<5)|0x10
// xor within group: src = (lane & 0x1f) ^ m                        -> PAT = (m<<10)|0x1f
template <int PAT>
__device__ __forceinline__ float swz(float v) {
    return __int_as_float(__builtin_amdgcn_ds_swizzle(__float_as_int(v), PAT));
}

// stable softplus (setup only)
__device__ __forceinline__ float softplus_f(float x) {
    return fmaxf(x, 0.0f) + log1pf(expf(-fabsf(x)));
}
__device__ __forceinline__ float samp(const float* mu, const float* rho,
                                      const float* eps, int i) {
    return mu[i] + softplus_f(rho[i]) * eps[i];
}

// sigmoid = rcp(1 + 2^(-log2e * x)); v_mul + v_exp + v_add + v_rcp
__device__ __forceinline__ float fast_sigmoid(float x) {
    float e = __builtin_amdgcn_exp2f(-1.442695040888963f * x);
    return __builtin_amdgcn_rcpf(1.0f + e);
}
// tanh(x) = 1 - 2/(2^(2*log2e*x) + 1); saturates correctly
__device__ __forceinline__ float fast_tanh(float x) {
    float e = __builtin_amdgcn_exp2f(2.885390081777927f * x);
    return fmaf(-2.0f, __builtin_amdgcn_rcpf(e + 1.0f), 1.0f);
}

// one recurrence step: broadcast h_j via immediate ds_swizzle, split-accumulate
#define GATE_J(J)                                                        \
    {                                                                    \
        float hj = swz<((J) << 5) | 0x10>(hk);                           \
        v2f hj2 = mk2(hj, hj);                                           \
        if ((J) % 2 == 0) {                                              \
            a01 = __builtin_elementwise_fma(hj2, whh01[J], a01);         \
            a23 = __builtin_elementwise_fma(hj2, whh23[J], a23);         \
        } else {                                                         \
            a01o = __builtin_elementwise_fma(hj2, whh01[J], a01o);       \
            a23o = __builtin_elementwise_fma(hj2, whh23[J], a23o);       \
        }                                                                \
    }

#define TSTEP(TI)                                                        \
    {                                                                    \
        float xt = swz<((TI) << 5) | 0x10>(xcur);                        \
        v2f xt2 = mk2(xt, xt);                                           \
        v2f a01 = __builtin_elementwise_fma(xt2, wih01, b01);            \
        v2f a23 = __builtin_elementwise_fma(xt2, wih23, b23);            \
        v2f a01o = mk2(0.f, 0.f), a23o = mk2(0.f, 0.f);                  \
        GATE_J(0) GATE_J(1) GATE_J(2) GATE_J(3) GATE_J(4)                \
        GATE_J(5) GATE_J(6) GATE_J(7) GATE_J(8) GATE_J(9)                \
        a01 = a01 + a01o;                                                \
        a23 = a23 + a23o;                                                \
        float ig = fast_sigmoid(a01.x);                                  \
        float fg = fast_sigmoid(a01.y);                                  \
        float gg = fast_tanh(a23.x);                                     \
        float og = fast_sigmoid(a23.y);                                  \
        c = fmaf(fg, c, ig * gg);                                        \
        hk = og * fast_tanh(c);                                          \
    }

__global__ __launch_bounds__(256) void bayes_lstm_kernel(
    const float* __restrict__ x,
    const float* __restrict__ w_ih_mu, const float* __restrict__ w_ih_rho,
    const float* __restrict__ w_hh_mu, const float* __restrict__ w_hh_rho,
    const float* __restrict__ b_mu,    const float* __restrict__ b_rho,
    const float* __restrict__ eps_ih,  const float* __restrict__ eps_hh,
    const float* __restrict__ eps_b,
    const float* __restrict__ lin_w,   const float* __restrict__ lin_b,
    float* __restrict__ out)
{
    const int tid   = threadIdx.x;
    const int k     = tid & 15;        // hidden unit (active: k < 10)
    const int group = tid >> 4;
    const int b     = blockIdx.x * 16 + group;

    // ---- sample weights into registers (zero-padded for lanes 10..15) ----
    v2f whh01[HID], whh23[HID];
    v2f wih01 = mk2(0.f, 0.f), wih23 = mk2(0.f, 0.f);
    v2f b01   = mk2(0.f, 0.f), b23   = mk2(0.f, 0.f);
#pragma unroll
    for (int j = 0; j < HID; ++j) { whh01[j] = mk2(0.f, 0.f); whh23[j] = mk2(0.f, 0.f); }

    float lw = 0.f;
    if (k < HID) {
        const int c0 = k, c1 = HID + k, c2 = 2 * HID + k, c3 = 3 * HID + k;
        wih01 = mk2(samp(w_ih_mu, w_ih_rho, eps_ih, c0), samp(w_ih_mu, w_ih_rho, eps_ih, c1));
        wih23 = mk2(samp(w_ih_mu, w_ih_rho, eps_ih, c2), samp(w_ih_mu, w_ih_rho, eps_ih, c3));
        b01   = mk2(samp(b_mu, b_rho, eps_b, c0), samp(b_mu, b_rho, eps_b, c1));
        b23   = mk2(samp(b_mu, b_rho, eps_b, c2), samp(b_mu, b_rho, eps_b, c3));
#pragma unroll
        for (int j = 0; j < HID; ++j) {
            whh01[j] = mk2(samp(w_hh_mu, w_hh_rho, eps_hh, j * 4 * HID + c0),
                           samp(w_hh_mu, w_hh_rho, eps_hh, j * 4 * HID + c1));
            whh23[j] = mk2(samp(w_hh_mu, w_hh_rho, eps_hh, j * 4 * HID + c2),
                           samp(w_hh_mu, w_hh_rho, eps_hh, j * 4 * HID + c3));
        }
        lw = lin_w[k];
    }

    // ---- LSTM recurrence ----
    float hk = 0.0f;   // this lane's hidden unit
    float c  = 0.0f;

    const float* xrow = x + (size_t)b * T_LEN;
    float xcur = xrow[k];              // chunk 0: lane k holds x[t = k]

    for (int to = 0; to < 16; ++to) {
        float xnext = 0.0f;
        if (to < 15) xnext = xrow[(to + 1) * 16 + k];   // prefetch next chunk
        TSTEP(0)  TSTEP(1)  TSTEP(2)  TSTEP(3)
        TSTEP(4)  TSTEP(5)  TSTEP(6)  TSTEP(7)
        TSTEP(8)  TSTEP(9)  TSTEP(10) TSTEP(11)
        TSTEP(12) TSTEP(13) TSTEP(14) TSTEP(15)
        xcur = xnext;
    }

    // ---- linear head: xor-swizzle reduction over the 16-lane group ----
    float part = hk * lw;              // lanes >= 10 contribute 0
    part += swz<(1 << 10) | 0x1f>(part);
    part += swz<(2 << 10) | 0x1f>(part);
    part += swz<(4 << 10) | 0x1f>(part);
    part += swz<(8 << 10) | 0x1f>(part);
    if (k == 0) out[b] = part + lin_b[0];
}

extern "C" void kernel_launch(void* const* d_in, const int* in_sizes, int n_in,
                              void* d_out, int out_size, void* d_ws, size_t ws_size,
                              hipStream_t stream) {
    const float* x        = (const float*)d_in[0];
    const float* w_ih_mu  = (const float*)d_in[1];
    const float* w_ih_rho = (const float*)d_in[2];
    const float* w_hh_mu  = (const float*)d_in[3];
    const float* w_hh_rho = (const float*)d_in[4];
    const float* b_mu     = (const float*)d_in[5];
    const float* b_rho    = (const float*)d_in[6];
    const float* eps_ih   = (const float*)d_in[7];
    const float* eps_hh   = (const float*)d_in[8];
    const float* eps_b    = (const float*)d_in[9];
    const float* lin_w    = (const float*)d_in[10];
    const float* lin_b    = (const float*)d_in[11];
    float* out = (float*)d_out;

    const int n_b = in_sizes[0] / T_LEN;     // 8192
    dim3 grid(n_b / 16), block(256);
    hipLaunchKernelGGL(bayes_lstm_kernel, grid, block, 0, stream,
                       x, w_ih_mu, w_ih_rho, w_hh_mu, w_hh_rho, b_mu, b_rho,
                       eps_ih, eps_hh, eps_b, lin_w, lin_b, out);
}

// Round 3
// 163.943 us; speedup vs baseline: 1.0348x; 1.0266x over previous
//
#include <hip/hip_runtime.h>
#include <math.h>

#define T_LEN 256
#define HID 10

typedef float v2f __attribute__((ext_vector_type(2)));

__device__ __forceinline__ v2f mk2(float a, float b) { v2f r; r.x = a; r.y = b; return r; }
__device__ __forceinline__ v2f splat2(float a) { return mk2(a, a); }

// setup-only accurate softplus
__device__ __forceinline__ float softplus_f(float x) {
    return fmaxf(x, 0.0f) + log1pf(expf(-fabsf(x)));
}
__device__ __forceinline__ float samp(const float* mu, const float* rho,
                                      const float* eps, int i) {
    return mu[i] + softplus_f(rho[i]) * eps[i];
}

// sigmoid = rcp(1 + 2^(-log2e*x))
__device__ __forceinline__ float fast_sigmoid(float x) {
    float e = __builtin_amdgcn_exp2f(-1.442695040888963f * x);
    return __builtin_amdgcn_rcpf(1.0f + e);
}
// tanh(x) = 1 - 2/(2^(2*log2e*x)+1)
__device__ __forceinline__ float fast_tanh(float x) {
    float e = __builtin_amdgcn_exp2f(2.885390081777927f * x);
    return fmaf(-2.0f, __builtin_amdgcn_rcpf(e + 1.0f), 1.0f);
}

struct Wreg {
    v2f whh01[HID], whh23[HID];   // recurrent cols {i,f} / {g,o} for this lane's unit
    v2f wih01, wih23, b01, b23;
};

// one LSTM step for one element; h comes in as 3 float4s (h[0..9] + 2 pad)
__device__ __forceinline__ float lstm_step(const Wreg& w, float xt,
                                           float4 h0, float4 h1, float4 h2,
                                           float& c)
{
    v2f x2 = splat2(xt);
    // even-j chain (seeded with x/bias) and odd-j chain, combined once
    v2f e01 = __builtin_elementwise_fma(x2, w.wih01, w.b01);
    v2f e23 = __builtin_elementwise_fma(x2, w.wih23, w.b23);
    v2f o01 = w.whh01[1] * splat2(h0.y);
    v2f o23 = w.whh23[1] * splat2(h0.y);
    e01 = __builtin_elementwise_fma(splat2(h0.x), w.whh01[0], e01);
    e23 = __builtin_elementwise_fma(splat2(h0.x), w.whh23[0], e23);
    o01 = __builtin_elementwise_fma(splat2(h0.w), w.whh01[3], o01);
    o23 = __builtin_elementwise_fma(splat2(h0.w), w.whh23[3], o23);
    e01 = __builtin_elementwise_fma(splat2(h0.z), w.whh01[2], e01);
    e23 = __builtin_elementwise_fma(splat2(h0.z), w.whh23[2], e23);
    o01 = __builtin_elementwise_fma(splat2(h1.y), w.whh01[5], o01);
    o23 = __builtin_elementwise_fma(splat2(h1.y), w.whh23[5], o23);
    e01 = __builtin_elementwise_fma(splat2(h1.x), w.whh01[4], e01);
    e23 = __builtin_elementwise_fma(splat2(h1.x), w.whh23[4], e23);
    o01 = __builtin_elementwise_fma(splat2(h1.w), w.whh01[7], o01);
    o23 = __builtin_elementwise_fma(splat2(h1.w), w.whh23[7], o23);
    e01 = __builtin_elementwise_fma(splat2(h1.z), w.whh01[6], e01);
    e23 = __builtin_elementwise_fma(splat2(h1.z), w.whh23[6], e23);
    o01 = __builtin_elementwise_fma(splat2(h2.y), w.whh01[9], o01);
    o23 = __builtin_elementwise_fma(splat2(h2.y), w.whh23[9], o23);
    e01 = __builtin_elementwise_fma(splat2(h2.x), w.whh01[8], e01);
    e23 = __builtin_elementwise_fma(splat2(h2.x), w.whh23[8], e23);
    v2f a01 = e01 + o01;
    v2f a23 = e23 + o23;
    float ig = fast_sigmoid(a01.x);
    float fg = fast_sigmoid(a01.y);
    float gg = fast_tanh(a23.x);
    float og = fast_sigmoid(a23.y);
    c = fmaf(fg, c, ig * gg);
    return og * fast_tanh(c);
}

__global__ __launch_bounds__(256) void bayes_lstm_kernel(
    const float* __restrict__ x,
    const float* __restrict__ w_ih_mu, const float* __restrict__ w_ih_rho,
    const float* __restrict__ w_hh_mu, const float* __restrict__ w_hh_rho,
    const float* __restrict__ b_mu,    const float* __restrict__ b_rho,
    const float* __restrict__ eps_ih,  const float* __restrict__ eps_hh,
    const float* __restrict__ eps_b,
    const float* __restrict__ lin_w,   const float* __restrict__ lin_b,
    float* __restrict__ out)
{
    // 16 slots/block x 2 elements/slot, 12 floats (48B) per element:
    // b128 reads are 16B-aligned and bank-disjoint across groups; writes <=2-way.
    __shared__ __align__(16) float hbuf[16 * 2 * 12];

    const int tid   = threadIdx.x;
    const int k     = tid & 15;          // hidden unit (active: k < 10)
    const int slot  = tid >> 4;          // 0..15
    const int gslot = blockIdx.x * 16 + slot;
    const int bA    = gslot * 2, bB = bA + 1;
    const int ibA   = slot * 24, ibB = ibA + 12;

    // ---- sample weights into registers (shared by both elements) ----
    Wreg w;
#pragma unroll
    for (int j = 0; j < HID; ++j) { w.whh01[j] = splat2(0.f); w.whh23[j] = splat2(0.f); }
    w.wih01 = splat2(0.f); w.wih23 = splat2(0.f);
    w.b01 = splat2(0.f);   w.b23 = splat2(0.f);
    float lw = 0.f;
    if (k < HID) {
        const int c0 = k, c1 = HID + k, c2 = 2 * HID + k, c3 = 3 * HID + k;
        w.wih01 = mk2(samp(w_ih_mu, w_ih_rho, eps_ih, c0), samp(w_ih_mu, w_ih_rho, eps_ih, c1));
        w.wih23 = mk2(samp(w_ih_mu, w_ih_rho, eps_ih, c2), samp(w_ih_mu, w_ih_rho, eps_ih, c3));
        w.b01   = mk2(samp(b_mu, b_rho, eps_b, c0), samp(b_mu, b_rho, eps_b, c1));
        w.b23   = mk2(samp(b_mu, b_rho, eps_b, c2), samp(b_mu, b_rho, eps_b, c3));
#pragma unroll
        for (int j = 0; j < HID; ++j) {
            w.whh01[j] = mk2(samp(w_hh_mu, w_hh_rho, eps_hh, j * 4 * HID + c0),
                             samp(w_hh_mu, w_hh_rho, eps_hh, j * 4 * HID + c1));
            w.whh23[j] = mk2(samp(w_hh_mu, w_hh_rho, eps_hh, j * 4 * HID + c2),
                             samp(w_hh_mu, w_hh_rho, eps_hh, j * 4 * HID + c3));
        }
        lw = lin_w[k];
        // zero-init h in LDS (wave-internal, in-order DS: no barrier needed)
        hbuf[ibA + k] = 0.f;
        hbuf[ibB + k] = 0.f;
    }

    float cA = 0.f, cB = 0.f, hkA = 0.f, hkB = 0.f;
    const float* xrA = x + (size_t)bA * T_LEN;
    const float* xrB = x + (size_t)bB * T_LEN;
    float xcA = xrA[k];                  // chunk 0: lane k holds x[t=k]
    float xcB = xrB[k];
    const float4* pA = (const float4*)(hbuf + ibA);
    const float4* pB = (const float4*)(hbuf + ibB);

    for (int to = 0; to < 16; ++to) {
        float xnA = 0.f, xnB = 0.f;
        if (to < 15) {                   // prefetch next chunk
            xnA = xrA[(to + 1) * 16 + k];
            xnB = xrB[(to + 1) * 16 + k];
        }
#pragma unroll
        for (int ti = 0; ti < 16; ++ti) {
            // read h (written by previous step; same-wave DS is in-order)
            float4 hA0 = pA[0], hA1 = pA[1], hA2 = pA[2];
            float4 hB0 = pB[0], hB1 = pB[1], hB2 = pB[2];
            float xa = __shfl(xcA, ti, 16);
            float xb = __shfl(xcB, ti, 16);
            hkA = lstm_step(w, xa, hA0, hA1, hA2, cA);
            hkB = lstm_step(w, xb, hB0, hB1, hB2, cB);
            if (k < HID) {
                hbuf[ibA + k] = hkA;
                hbuf[ibB + k] = hkB;
            }
        }
        xcA = xnA; xcB = xnB;
    }

    // ---- linear head: lanes k<10 hold final h[k]; reduce within 16-lane group ----
    float pa = hkA * lw;                 // lanes >= 10 contribute 0
    float pb = hkB * lw;
    pa += __shfl_xor(pa, 1, 16);  pb += __shfl_xor(pb, 1, 16);
    pa += __shfl_xor(pa, 2, 16);  pb += __shfl_xor(pb, 2, 16);
    pa += __shfl_xor(pa, 4, 16);  pb += __shfl_xor(pb, 4, 16);
    pa += __shfl_xor(pa, 8, 16);  pb += __shfl_xor(pb, 8, 16);
    if (k == 0) {
        float b0 = lin_b[0];
        out[bA] = pa + b0;
        out[bB] = pb + b0;
    }
}

extern "C" void kernel_launch(void* const* d_in, const int* in_sizes, int n_in,
                              void* d_out, int out_size, void* d_ws, size_t ws_size,
                              hipStream_t stream) {
    const float* x        = (const float*)d_in[0];
    const float* w_ih_mu  = (const float*)d_in[1];
    const float* w_ih_rho = (const float*)d_in[2];
    const float* w_hh_mu  = (const float*)d_in[3];
    const float* w_hh_rho = (const float*)d_in[4];
    const float* b_mu     = (const float*)d_in[5];
    const float* b_rho    = (const float*)d_in[6];
    const float* eps_ih   = (const float*)d_in[7];
    const float* eps_hh   = (const float*)d_in[8];
    const float* eps_b    = (const float*)d_in[9];
    const float* lin_w    = (const float*)d_in[10];
    const float* lin_b    = (const float*)d_in[11];
    float* out = (float*)d_out;

    const int n_b = in_sizes[0] / T_LEN;     // 8192
    dim3 grid(n_b / 32), block(256);         // 16 groups x 2 elements per block
    hipLaunchKernelGGL(bayes_lstm_kernel, grid, block, 0, stream,
                       x, w_ih_mu, w_ih_rho, w_hh_mu, w_hh_rho, b_mu, b_rho,
                       eps_ih, eps_hh, eps_b, lin_w, lin_b, out);
}